// Round 8
// baseline (267.721 us; speedup 1.0000x reference)
//
#include <hip/hip_runtime.h>
#include <hip/hip_bf16.h>

// Problem constants
constexpr int B_ = 512;
constexpr int T_ = 128;
constexpr int D_ = 768;
constexpr int CD_ = 192;
constexpr int SD_ = 128;
constexpr int P_ = 128;
constexpr int FEAT_ = 321;   // CD + SD + 1
constexpr float LN_EPS_ = 1e-5f;

constexpr size_t REP_SZ   = (size_t)B_ * 2 * D_;     // 786432 floats
constexpr size_t DN16_FLT = (size_t)P_ * D_ / 2;     // 49152 floats
// ws float layout: rep | dn16 | dot | part | h16
constexpr size_t FIXED_FLT = REP_SZ + DN16_FLT + B_ + CD_;   // 836288 floats
constexpr size_t H16_PER_B = (size_t)T_ * D_ * 2;            // bytes per batch

typedef __attribute__((ext_vector_type(8))) short short8;   // 8 bf16 (4 VGPRs)
typedef __attribute__((ext_vector_type(4))) float f32x4;

__device__ __forceinline__ unsigned short f2bf(float x) {
    unsigned u = __float_as_uint(x);
    return (unsigned short)((u + 0x7FFFu + ((u >> 16) & 1u)) >> 16);
}
__device__ __forceinline__ float bf2f(unsigned short h) {
    return __uint_as_float((unsigned)h << 16);
}

// ---------------------------------------------------------------------------
// Kernel 1: dirs_n = dirs / ||dirs||, bf16, PRE-SWIZZLED (chunk XOR by row)
// ---------------------------------------------------------------------------
__global__ __launch_bounds__(256) void k_dirs(const float* __restrict__ dirs,
                                              unsigned short* __restrict__ dn16) {
    int p = blockIdx.x;
    int tid = threadIdx.x;
    float s = 0.f;
    for (int d = tid; d < D_; d += 256) {
        float v = dirs[(size_t)p * D_ + d];
        s = fmaf(v, v, s);
    }
    __shared__ float red[256];
    red[tid] = s;
    __syncthreads();
    for (int off = 128; off > 0; off >>= 1) {
        if (tid < off) red[tid] += red[tid + off];
        __syncthreads();
    }
    float inv = 1.0f / sqrtf(red[0]);
    const int sz = ((p >> 1) & 3) << 3;       // chunk swizzle (8-elem units)
    for (int d = tid; d < D_; d += 256) {
        dn16[(size_t)p * D_ + (d ^ sz)] = f2bf(dirs[(size_t)p * D_ + d] * inv);
    }
}

// ---------------------------------------------------------------------------
// Kernel 2: k_prep — one streaming pass over H: rep (fp32) + H16 (bf16,
// pre-swizzled per row for the GEMM's linear global_load_lds staging).
// 192 threads: thread owns 4 consecutive d; float4 loads over t.
// ---------------------------------------------------------------------------
__global__ __launch_bounds__(192) void k_prep(const float* __restrict__ H,
                                              const int* __restrict__ tt,
                                              const int* __restrict__ attn,
                                              float* __restrict__ rep,
                                              unsigned short* __restrict__ h16,
                                              int bOff) {
    const int b = bOff + blockIdx.x;
    const int tid = threadIdx.x;
    __shared__ float m0s[T_], m1s[T_];
    __shared__ int ncnt[2];
    if (tid < 2) ncnt[tid] = 0;
    __syncthreads();
    if (tid < T_) {
        int t = tt[b * T_ + tid];
        int a = attn[b * T_ + tid];
        float m0 = (t == 0 && a == 1) ? 1.f : 0.f;
        float m1 = (t == 1 && a == 1) ? 1.f : 0.f;
        m0s[tid] = m0;
        m1s[tid] = m1;
        if (m0 > 0.f) atomicAdd(&ncnt[0], 1);
        if (m1 > 0.f) atomicAdd(&ncnt[1], 1);
    }
    __syncthreads();
    const float inv0 = 1.f / (float)max(ncnt[0], 1);
    const float inv1 = 1.f / (float)max(ncnt[1], 1);
    const float* Hb = H + (size_t)b * T_ * D_;
    unsigned short* h16b = h16 + (size_t)blockIdx.x * T_ * D_;
    float* repb = rep + (size_t)b * 2 * D_;
    const int d0 = tid * 4;          // 0..764

    // t = 0 peel (cls row, swizzle s=0)
    float4 h = *reinterpret_cast<const float4*>(Hb + d0);
    *reinterpret_cast<float4*>(repb + d0) = h;
    float s0x = h.x * m0s[0], s0y = h.y * m0s[0], s0z = h.z * m0s[0], s0w = h.w * m0s[0];
    float s1x = h.x * m1s[0], s1y = h.y * m1s[0], s1z = h.z * m1s[0], s1w = h.w * m1s[0];
    {
        ushort4 v;
        v.x = f2bf(h.x); v.y = f2bf(h.y); v.z = f2bf(h.z); v.w = f2bf(h.w);
        *reinterpret_cast<ushort4*>(h16b + d0) = v;
    }
#pragma unroll 4
    for (int t = 1; t < T_; ++t) {
        h = *reinterpret_cast<const float4*>(Hb + (size_t)t * D_ + d0);
        float m0 = m0s[t], m1 = m1s[t];
        s0x = fmaf(h.x, m0, s0x); s1x = fmaf(h.x, m1, s1x);
        s0y = fmaf(h.y, m0, s0y); s1y = fmaf(h.y, m1, s1y);
        s0z = fmaf(h.z, m0, s0z); s1z = fmaf(h.z, m1, s1z);
        s0w = fmaf(h.w, m0, s0w); s1w = fmaf(h.w, m1, s1w);
        ushort4 v;
        v.x = f2bf(h.x); v.y = f2bf(h.y); v.z = f2bf(h.z); v.w = f2bf(h.w);
        int dsw = d0 ^ (((t >> 1) & 3) << 3);    // chunk swizzle by row t
        *reinterpret_cast<ushort4*>(h16b + (size_t)t * D_ + dsw) = v;
    }
    float4 r;
    r.x = s0x * inv0 - s1x * inv1;
    r.y = s0y * inv0 - s1y * inv1;
    r.z = s0z * inv0 - s1z * inv1;
    r.w = s0w * inv0 - s1w * inv1;
    *reinterpret_cast<float4*>(repb + D_ + d0) = r;
}

// ---------------------------------------------------------------------------
// Kernel 3: pure MFMA proj GEMM (128x128 tile, global_load_lds staging,
// 3-buffer counted-vmcnt pipeline, 1 barrier/K-step) + key-rank + paired diff.
// 512 threads, one block per batch. LDS 51200 B.
// ---------------------------------------------------------------------------
constexpr int NIT_ = 24;            // 768 / 32

__global__ __launch_bounds__(512) void k_projsort(const int* __restrict__ tt,
                                                  const int* __restrict__ attn,
                                                  const unsigned short* __restrict__ h16,
                                                  const unsigned short* __restrict__ dn16,
                                                  float* __restrict__ d_ot,
                                                  int bOff) {
    const int b = bOff + blockIdx.x;
    const int tid = threadIdx.x;
    const int lane = tid & 63;
    const int w = tid >> 6;           // wave 0..7
    const int wr = w >> 2;            // row half
    const int wc = w & 3;             // col quarter
    const int fr = lane & 15;
    const int kg = lane >> 4;

    __shared__ __align__(16) unsigned short ldsbuf[24576];   // 48 KB: 3 x (A 4096 + B 4096)
    __shared__ float dred[512];                              // + ballot exchange
    unsigned short* proj16 = ldsbuf;                         // overlay (post-GEMM): 32 KB
    unsigned char* xb = (unsigned char*)(ldsbuf + 16384);    // [64][128]
    unsigned char* yb = xb + 8192;                           // [64][128]

    // --- phase 0: masks via ballot ---
    const int myt = 64 * wr + lane;
    int vt = tt[b * T_ + myt];
    int va = attn[b * T_ + myt];
    bool m0 = (vt == 0) && (va == 1);
    bool m1 = (vt == 1) && (va == 1);
    unsigned long long bal0 = __ballot(m0);
    unsigned long long bal1 = __ballot(m1);
    unsigned long long* xch = (unsigned long long*)dred;
    if (lane == 0 && (w == 0 || w == 4)) {
        xch[wr * 2] = bal0;
        xch[wr * 2 + 1] = bal1;
    }
    __syncthreads();
    const unsigned long long lo0 = xch[0], lo1 = xch[1], hi0 = xch[2], hi1 = xch[3];
    const int n0 = __popcll(lo0) + __popcll(hi0);
    const int n1 = __popcll(lo1) + __popcll(hi1);
    const int ntot = n0 + n1;
    unsigned long long below = (1ull << lane) - 1ull;
    int mypos = 0xFF;
    if (m0) mypos = (wr ? __popcll(lo0) : 0) + __popcll((wr ? hi0 : lo0) & below);
    else if (m1) mypos = n0 + (wr ? __popcll(lo1) : 0) + __popcll((wr ? hi1 : lo1) & below);
    __syncthreads();

    // --- phase 1: GEMM via global_load_lds pipeline ---
    const unsigned short* gAp = h16 + (size_t)blockIdx.x * T_ * D_ + (size_t)(tid >> 2) * D_ + (tid & 3) * 8;
    const unsigned short* gBp = dn16 + (size_t)(tid >> 2) * D_ + (tid & 3) * 8;

    int addrA[4], addrB[2];
#pragma unroll
    for (int m = 0; m < 4; ++m) {
        int row = 64 * wr + 16 * m + fr;
        addrA[m] = row * 32 + (kg ^ ((row >> 1) & 3)) * 8;
    }
#pragma unroll
    for (int n = 0; n < 2; ++n) {
        int row = 32 * wc + 16 * n + fr;
        addrB[n] = 4096 + row * 32 + (kg ^ ((row >> 1) & 3)) * 8;
    }

    f32x4 acc[4][2];
#pragma unroll
    for (int m = 0; m < 4; ++m)
#pragma unroll
        for (int n = 0; n < 2; ++n) acc[m][n] = (f32x4){0.f, 0.f, 0.f, 0.f};

    auto issue = [&](int it2) {
        const int bufo = (it2 % 3) * 8192;
        __builtin_amdgcn_global_load_lds((const void*)(gAp + it2 * 32),
                                         (void*)(&ldsbuf[bufo + w * 512]), 16, 0, 0);
        __builtin_amdgcn_global_load_lds((const void*)(gBp + it2 * 32),
                                         (void*)(&ldsbuf[bufo + 4096 + w * 512]), 16, 0, 0);
    };
    issue(0);
    issue(1);

    for (int it = 0; it < NIT_; ++it) {
        if (it < NIT_ - 1) asm volatile("s_waitcnt vmcnt(2)" ::: "memory");
        else               asm volatile("s_waitcnt vmcnt(0)" ::: "memory");
        __builtin_amdgcn_s_barrier();
        asm volatile("" ::: "memory");
        if (it + 2 < NIT_) issue(it + 2);
        const int bufo = (it % 3) * 8192;
        short8 af[4], bf_[2];
#pragma unroll
        for (int m = 0; m < 4; ++m)
            af[m] = *reinterpret_cast<const short8*>(&ldsbuf[bufo + addrA[m]]);
#pragma unroll
        for (int n = 0; n < 2; ++n)
            bf_[n] = *reinterpret_cast<const short8*>(&ldsbuf[bufo + addrB[n]]);
#pragma unroll
        for (int m = 0; m < 4; ++m)
#pragma unroll
            for (int n = 0; n < 2; ++n)
                acc[m][n] = __builtin_amdgcn_mfma_f32_16x16x32_bf16(af[m], bf_[n], acc[m][n], 0, 0, 0);
        asm volatile("" ::: "memory");
    }
    __syncthreads();   // all frag reads done; stage buffers now dead

    // epilogue: proj16 group-permuted (pos via shfl), sortable-u16
#pragma unroll
    for (int m = 0; m < 4; ++m) {
#pragma unroll
        for (int r = 0; r < 4; ++r) {
            int rowlane = 16 * m + kg * 4 + r;
            int pp = __shfl(mypos, rowlane);
            if (pp != 0xFF) {
#pragma unroll
                for (int n = 0; n < 2; ++n) {
                    int col = 32 * wc + 16 * n + fr;
                    unsigned bb = f2bf(acc[m][n][r]);
                    unsigned su = bb ^ ((bb >> 15) ? 0xFFFFu : 0x8000u);
                    proj16[pp * 128 + col] = (unsigned short)su;
                }
            }
        }
    }
    __syncthreads();

    // --- phase 2: ranking via sortable-u32 keys, 2 passes x 16 keys ---
    const int mmv = min(n0, n1);      // <= 64
    const int c = tid & 127;
    const int q = tid >> 7;           // 0..3
#pragma unroll
    for (int pass = 0; pass < 2; ++pass) {
        const int pbase = q * 32 + pass * 16;
        unsigned kv[16];
        int cnt[16];
#pragma unroll
        for (int ii = 0; ii < 16; ++ii) {
            int p = pbase + ii;
            unsigned key = 0xFFFFFFFFu;
            if (p < ntot) {
                unsigned su = proj16[p * 128 + c];
                key = ((unsigned)(p >= n0) << 31) | (su << 8) | (unsigned)p;
            }
            kv[ii] = key;
            cnt[ii] = 0;
        }
        int lo, hi;
        if (pbase + 16 <= n0) { lo = 0;  hi = n0;   }
        else if (pbase >= n0) { lo = n0; hi = ntot; }
        else                  { lo = 0;  hi = ntot; }
        for (int j = lo; j < hi; ++j) {
            unsigned su = proj16[j * 128 + c];
            unsigned kw = ((unsigned)(j >= n0) << 31) | (su << 8) | (unsigned)j;
#pragma unroll
            for (int ii = 0; ii < 16; ++ii) cnt[ii] += (kw < kv[ii]) ? 1 : 0;
        }
#pragma unroll
        for (int ii = 0; ii < 16; ++ii) {
            int p = pbase + ii;
            if (p < ntot) {
                int rank = cnt[ii] - ((p >= n0 && lo == 0) ? n0 : 0);
                if (rank < mmv) {
                    unsigned char* buf = (p >= n0) ? yb : xb;
                    buf[rank * 128 + c] = (unsigned char)p;
                }
            }
        }
    }
    __syncthreads();

    // --- phase 3: paired diff per column, max over columns ---
    float part = 0.f;
    for (int r = q; r < mmv; r += 4) {
        unsigned sx = proj16[(int)xb[r * 128 + c] * 128 + c];
        unsigned sy = proj16[(int)yb[r * 128 + c] * 128 + c];
        unsigned bx = sx ^ ((sx >> 15) ? 0x8000u : 0xFFFFu);
        unsigned byv = sy ^ ((sy >> 15) ? 0x8000u : 0xFFFFu);
        part += fabsf(bf2f((unsigned short)bx) - bf2f((unsigned short)byv));
    }
    dred[tid] = part;
    __syncthreads();
    if (tid < 128) {
        float invm = 1.f / (float)max(mmv, 1);
        dred[tid] = (dred[tid] + dred[tid + 128] + dred[tid + 256] + dred[tid + 384]) * invm;
    }
    __syncthreads();
    if (tid < 64) {
        float m = fmaxf(dred[tid], dred[tid + 64]);
#pragma unroll
        for (int off = 32; off > 0; off >>= 1) m = fmaxf(m, __shfl_xor(m, off));
        if (tid == 0) d_ot[b] = m;
    }
}

// ---------------------------------------------------------------------------
// Kernel 4: head — C/S GEMV + gate + LayerNorm + logits.
// ---------------------------------------------------------------------------
__global__ __launch_bounds__(320) void k_head(const float* __restrict__ rep,
                                              const float* __restrict__ Wc,
                                              const float* __restrict__ bc,
                                              const float* __restrict__ Ws,
                                              const float* __restrict__ bs,
                                              const float* __restrict__ gate,
                                              const float* __restrict__ lng,
                                              const float* __restrict__ lnb,
                                              const float* __restrict__ Wcls,
                                              const float* __restrict__ bcls,
                                              const float* __restrict__ d_ot,
                                              float* __restrict__ out) {
    int b0 = blockIdx.x * 4;
    int tid = threadIdx.x;
    __shared__ __align__(16) float repS[4 * 1536];
    __shared__ float featS[4 * FEAT_];

    const float4* repg = reinterpret_cast<const float4*>(rep + (size_t)b0 * 1536);
    float4* repl = reinterpret_cast<float4*>(repS);
    for (int i = tid; i < 1536; i += 320) repl[i] = repg[i];
    __syncthreads();

    float g = 1.f / (1.f + expf(-gate[0]));

    {
        int o = tid;  // 0..319
        bool isC = o < CD_;
        const float* w = isC ? (Wc + (size_t)o * 1536) : (Ws + (size_t)(o - CD_) * 1536);
        float bias = isC ? bc[o] : bs[o - CD_];
        float scale = isC ? (1.f - g) : g;
        const float4* w4 = reinterpret_cast<const float4*>(w);
        float a0 = 0.f, a1 = 0.f, a2 = 0.f, a3 = 0.f;
        for (int k4 = 0; k4 < 384; ++k4) {
            float4 wv = w4[k4];
            float4 r0 = repl[k4];
            float4 r1 = repl[384 + k4];
            float4 r2 = repl[768 + k4];
            float4 r3 = repl[1152 + k4];
            a0 += fmaf(wv.x, r0.x, fmaf(wv.y, r0.y, fmaf(wv.z, r0.z, wv.w * r0.w)));
            a1 += fmaf(wv.x, r1.x, fmaf(wv.y, r1.y, fmaf(wv.z, r1.z, wv.w * r1.w)));
            a2 += fmaf(wv.x, r2.x, fmaf(wv.y, r2.y, fmaf(wv.z, r2.z, wv.w * r2.w)));
            a3 += fmaf(wv.x, r3.x, fmaf(wv.y, r3.y, fmaf(wv.z, r3.z, wv.w * r3.w)));
        }
        featS[0 * FEAT_ + o] = (a0 + bias) * scale;
        featS[1 * FEAT_ + o] = (a1 + bias) * scale;
        featS[2 * FEAT_ + o] = (a2 + bias) * scale;
        featS[3 * FEAT_ + o] = (a3 + bias) * scale;
    }
    if (tid < 4) featS[tid * FEAT_ + 320] = d_ot[b0 + tid];
    __syncthreads();

    int w = tid >> 6, lane = tid & 63;
    if (w < 4) {
        const float* f = featS + w * FEAT_;
        float s = 0.f, s2 = 0.f;
        for (int i = lane; i < FEAT_; i += 64) {
            float v = f[i];
            s += v;
            s2 = fmaf(v, v, s2);
        }
#pragma unroll
        for (int off = 32; off > 0; off >>= 1) {
            s += __shfl_xor(s, off);
            s2 += __shfl_xor(s2, off);
        }
        float mu = s * (1.f / (float)FEAT_);
        float var = fmaxf(s2 * (1.f / (float)FEAT_) - mu * mu, 0.f);
        float rstd = 1.0f / sqrtf(var + LN_EPS_);
        float l0 = 0.f, l1 = 0.f;
        for (int i = lane; i < FEAT_; i += 64) {
            float nv = (f[i] - mu) * rstd * lng[i] + lnb[i];
            l0 = fmaf(nv, Wcls[i], l0);
            l1 = fmaf(nv, Wcls[FEAT_ + i], l1);
        }
#pragma unroll
        for (int off = 32; off > 0; off >>= 1) {
            l0 += __shfl_xor(l0, off);
            l1 += __shfl_xor(l1, off);
        }
        if (lane == 0) {
            out[(size_t)(b0 + w) * 2 + 0] = l0 + bcls[0];
            out[(size_t)(b0 + w) * 2 + 1] = l1 + bcls[1];
        }
    }
}

// ---------------------------------------------------------------------------
// Kernel 5/6: ortho = mean((Wc @ Ws^T)^2)
// ---------------------------------------------------------------------------
__global__ __launch_bounds__(256) void k_ortho(const float* __restrict__ Wc,
                                               const float* __restrict__ Ws,
                                               float* __restrict__ part) {
    int i = blockIdx.x;
    int tid = threadIdx.x;
    __shared__ float wrow[1536];
    __shared__ float tmp[256];
    for (int k = tid; k < 1536; k += 256) wrow[k] = Wc[(size_t)i * 1536 + k];
    __syncthreads();
    int j = tid & 127, h = tid >> 7;
    const float* wsr = Ws + (size_t)j * 1536 + h * 768;
    const float* wr = wrow + h * 768;
    float s = 0.f;
    for (int k = 0; k < 768; ++k) s = fmaf(wr[k], wsr[k], s);
    tmp[tid] = s;
    __syncthreads();
    if (tid < 128) {
        float d = tmp[tid] + tmp[tid + 128];
        tmp[tid] = d * d;
    }
    __syncthreads();
    for (int off = 64; off > 0; off >>= 1) {
        if (tid < off) tmp[tid] += tmp[tid + off];
        __syncthreads();
    }
    if (tid == 0) part[i] = tmp[0];
}

__global__ __launch_bounds__(256) void k_ortho2(const float* __restrict__ part,
                                                float* __restrict__ out) {
    int tid = threadIdx.x;
    __shared__ float red[256];
    red[tid] = (tid < CD_) ? part[tid] : 0.f;
    __syncthreads();
    for (int off = 128; off > 0; off >>= 1) {
        if (tid < off) red[tid] += red[tid + off];
        __syncthreads();
    }
    if (tid == 0) out[(size_t)B_ * 2] = red[0] / (float)(CD_ * SD_);
}

// ---------------------------------------------------------------------------
extern "C" void kernel_launch(void* const* d_in, const int* in_sizes, int n_in,
                              void* d_out, int out_size, void* d_ws, size_t ws_size,
                              hipStream_t stream) {
    const float* H    = (const float*)d_in[0];
    const int*   tt   = (const int*)d_in[1];
    const int*   attn = (const int*)d_in[2];
    const float* Wc   = (const float*)d_in[3];
    const float* bc   = (const float*)d_in[4];
    const float* Ws   = (const float*)d_in[5];
    const float* bs   = (const float*)d_in[6];
    const float* gate = (const float*)d_in[7];
    const float* lng  = (const float*)d_in[8];
    const float* lnb  = (const float*)d_in[9];
    const float* Wcls = (const float*)d_in[10];
    const float* bcls = (const float*)d_in[11];
    const float* dirs = (const float*)d_in[12];

    float* ws    = (float*)d_ws;
    float* rep   = ws;                                      // [B][1536] fp32
    unsigned short* dn16 = (unsigned short*)(ws + REP_SZ);  // [P][D] bf16 (swizzled)
    float* dot   = ws + REP_SZ + DN16_FLT;                  // [B]
    float* part  = dot + B_;                                // [CD]
    unsigned short* h16 = (unsigned short*)(ws + FIXED_FLT);// [chunk][T][D] bf16 (swizzled)
    float* out   = (float*)d_out;

    // batch chunk size limited by workspace
    size_t availB = (ws_size > FIXED_FLT * 4) ? (ws_size - FIXED_FLT * 4) : 0;
    int maxB = (int)(availB / H16_PER_B);
    int chunk = B_;
    while (chunk > maxB && chunk > 1) chunk >>= 1;
    if (chunk > maxB) chunk = 1;

    k_dirs<<<P_, 256, 0, stream>>>(dirs, dn16);
    for (int c = 0; c < B_; c += chunk) {
        int nb = min(chunk, B_ - c);
        k_prep<<<nb, 192, 0, stream>>>(H, tt, attn, rep, h16, c);
        k_projsort<<<nb, 512, 0, stream>>>(tt, attn, h16, dn16, dot, c);
    }
    k_head<<<B_ / 4, 320, 0, stream>>>(rep, Wc, bc, Ws, bs, gate, lng, lnb, Wcls, bcls, dot, out);
    k_ortho<<<CD_, 256, 0, stream>>>(Wc, Ws, part);
    k_ortho2<<<1, 256, 0, stream>>>(part, out);
}

// Round 9
// 240.353 us; speedup vs baseline: 1.1139x; 1.1139x over previous
//
#include <hip/hip_runtime.h>
#include <hip/hip_bf16.h>

// Problem constants
constexpr int B_ = 512;
constexpr int T_ = 128;
constexpr int D_ = 768;
constexpr int CD_ = 192;
constexpr int SD_ = 128;
constexpr int P_ = 128;
constexpr int FEAT_ = 321;   // CD + SD + 1
constexpr float LN_EPS_ = 1e-5f;

constexpr size_t REP_SZ   = (size_t)B_ * 2 * D_;     // 786432 floats
constexpr size_t DN16_FLT = (size_t)P_ * D_ / 2;     // 49152 floats
// ws float layout: rep | dn16 | dot | part | h16
constexpr size_t FIXED_FLT = REP_SZ + DN16_FLT + B_ + CD_;   // 836288 floats
constexpr size_t H16_PER_B = (size_t)T_ * D_ * 2;            // bytes per batch

typedef __attribute__((ext_vector_type(8))) short short8;   // 8 bf16 (4 VGPRs)
typedef __attribute__((ext_vector_type(4))) float f32x4;

__device__ __forceinline__ unsigned short f2bf(float x) {
    unsigned u = __float_as_uint(x);
    return (unsigned short)((u + 0x7FFFu + ((u >> 16) & 1u)) >> 16);
}
__device__ __forceinline__ float bf2f(unsigned short h) {
    return __uint_as_float((unsigned)h << 16);
}

// ---------------------------------------------------------------------------
// Kernel 1: dirs_n = dirs / ||dirs||, bf16, PRE-SWIZZLED (chunk XOR by row)
// ---------------------------------------------------------------------------
__global__ __launch_bounds__(256) void k_dirs(const float* __restrict__ dirs,
                                              unsigned short* __restrict__ dn16) {
    int p = blockIdx.x;
    int tid = threadIdx.x;
    float s = 0.f;
    for (int d = tid; d < D_; d += 256) {
        float v = dirs[(size_t)p * D_ + d];
        s = fmaf(v, v, s);
    }
    __shared__ float red[256];
    red[tid] = s;
    __syncthreads();
    for (int off = 128; off > 0; off >>= 1) {
        if (tid < off) red[tid] += red[tid + off];
        __syncthreads();
    }
    float inv = 1.0f / sqrtf(red[0]);
    const int sz = ((p >> 1) & 3) << 3;       // chunk swizzle (8-elem units)
    for (int d = tid; d < D_; d += 256) {
        dn16[(size_t)p * D_ + (d ^ sz)] = f2bf(dirs[(size_t)p * D_ + d] * inv);
    }
}

// ---------------------------------------------------------------------------
// Kernel 2: k_prep v2 — streaming pass over H: rep (fp32) + H16 (bf16,
// pre-swizzled). 768 threads = 4 t-slices x 192 d-groups; LDS slice-reduce.
// ---------------------------------------------------------------------------
__global__ __launch_bounds__(768) void k_prep(const float* __restrict__ H,
                                              const int* __restrict__ tt,
                                              const int* __restrict__ attn,
                                              float* __restrict__ rep,
                                              unsigned short* __restrict__ h16,
                                              int bOff) {
    const int b = bOff + blockIdx.x;
    const int tid = threadIdx.x;
    const int s = tid / 192;         // t-slice 0..3 (wave-uniform: 192 = 3 waves)
    const int g = tid % 192;         // d-group
    const int d0 = g * 4;
    __shared__ float m0s[T_], m1s[T_];
    __shared__ int ncnt[2];
    __shared__ __align__(16) float redS[4 * 192 * 8];   // 24 KB

    if (tid < 2) ncnt[tid] = 0;
    __syncthreads();
    if (tid < T_) {
        int t = tt[b * T_ + tid];
        int a = attn[b * T_ + tid];
        float m0 = (t == 0 && a == 1) ? 1.f : 0.f;
        float m1 = (t == 1 && a == 1) ? 1.f : 0.f;
        m0s[tid] = m0;
        m1s[tid] = m1;
        if (m0 > 0.f) atomicAdd(&ncnt[0], 1);
        if (m1 > 0.f) atomicAdd(&ncnt[1], 1);
    }
    __syncthreads();
    const float inv0 = 1.f / (float)max(ncnt[0], 1);
    const float inv1 = 1.f / (float)max(ncnt[1], 1);
    const float* Hb = H + (size_t)b * T_ * D_;
    unsigned short* h16b = h16 + (size_t)blockIdx.x * T_ * D_;
    float* repb = rep + (size_t)b * 2 * D_;

    float s00 = 0.f, s01 = 0.f, s02 = 0.f, s03 = 0.f;
    float s10 = 0.f, s11 = 0.f, s12 = 0.f, s13 = 0.f;
    const int t0 = s * 32;
#pragma unroll 4
    for (int ti = 0; ti < 32; ++ti) {
        int t = t0 + ti;
        float4 h = *reinterpret_cast<const float4*>(Hb + (size_t)t * D_ + d0);
        float m0 = m0s[t], m1 = m1s[t];
        s00 = fmaf(h.x, m0, s00); s10 = fmaf(h.x, m1, s10);
        s01 = fmaf(h.y, m0, s01); s11 = fmaf(h.y, m1, s11);
        s02 = fmaf(h.z, m0, s02); s12 = fmaf(h.z, m1, s12);
        s03 = fmaf(h.w, m0, s03); s13 = fmaf(h.w, m1, s13);
        ushort4 v;
        v.x = f2bf(h.x); v.y = f2bf(h.y); v.z = f2bf(h.z); v.w = f2bf(h.w);
        int dsw = d0 ^ (((t >> 1) & 3) << 3);    // chunk swizzle by row t
        *reinterpret_cast<ushort4*>(h16b + (size_t)t * D_ + dsw) = v;
        if (s == 0 && ti == 0) {                 // cls = H[b,0,:] exact fp32
            *reinterpret_cast<float4*>(repb + d0) = h;
        }
    }
    float* rs = &redS[(s * 192 + g) * 8];
    *reinterpret_cast<float4*>(rs)     = (float4){s00, s01, s02, s03};
    *reinterpret_cast<float4*>(rs + 4) = (float4){s10, s11, s12, s13};
    __syncthreads();
    if (s == 0) {
        float a0 = 0.f, a1 = 0.f, a2 = 0.f, a3 = 0.f;
        float b0 = 0.f, b1 = 0.f, b2 = 0.f, b3 = 0.f;
#pragma unroll
        for (int k = 0; k < 4; ++k) {
            const float* r = &redS[(k * 192 + g) * 8];
            a0 += r[0]; a1 += r[1]; a2 += r[2]; a3 += r[3];
            b0 += r[4]; b1 += r[5]; b2 += r[6]; b3 += r[7];
        }
        float4 rr;
        rr.x = a0 * inv0 - b0 * inv1;
        rr.y = a1 * inv0 - b1 * inv1;
        rr.z = a2 * inv0 - b2 * inv1;
        rr.w = a3 * inv0 - b3 * inv1;
        *reinterpret_cast<float4*>(repb + D_ + d0) = rr;
    }
}

// ---------------------------------------------------------------------------
// Kernel 3: pure MFMA proj GEMM (128x128 tile, global_load_lds staging,
// 4-buffer 3-ahead counted-vmcnt pipeline, 1 barrier/K-step) + key-rank + diff.
// 512 threads, one block per batch. LDS ~66 KB.
// ---------------------------------------------------------------------------
constexpr int NIT_ = 24;            // 768 / 32

__global__ __launch_bounds__(512) void k_projsort(const int* __restrict__ tt,
                                                  const int* __restrict__ attn,
                                                  const unsigned short* __restrict__ h16,
                                                  const unsigned short* __restrict__ dn16,
                                                  float* __restrict__ d_ot,
                                                  int bOff) {
    const int b = bOff + blockIdx.x;
    const int tid = threadIdx.x;
    const int lane = tid & 63;
    const int w = tid >> 6;           // wave 0..7
    const int wr = w >> 2;            // row half
    const int wc = w & 3;             // col quarter
    const int fr = lane & 15;
    const int kg = lane >> 4;

    __shared__ __align__(16) unsigned short ldsbuf[32768];   // 64 KB: 4 x (A 4096 + B 4096)
    __shared__ float dred[512];                              // + ballot exchange
    unsigned short* proj16 = ldsbuf;                         // overlay (post-GEMM): 32 KB (bufs 0-1)
    unsigned char* xb = (unsigned char*)(ldsbuf + 16384);    // [64][128] (buf 2)
    unsigned char* yb = xb + 8192;                           // [64][128] (buf 3)

    // --- phase 0: masks via ballot ---
    const int myt = 64 * wr + lane;
    int vt = tt[b * T_ + myt];
    int va = attn[b * T_ + myt];
    bool m0 = (vt == 0) && (va == 1);
    bool m1 = (vt == 1) && (va == 1);
    unsigned long long bal0 = __ballot(m0);
    unsigned long long bal1 = __ballot(m1);
    unsigned long long* xch = (unsigned long long*)dred;
    if (lane == 0 && (w == 0 || w == 4)) {
        xch[wr * 2] = bal0;
        xch[wr * 2 + 1] = bal1;
    }
    __syncthreads();
    const unsigned long long lo0 = xch[0], lo1 = xch[1], hi0 = xch[2], hi1 = xch[3];
    const int n0 = __popcll(lo0) + __popcll(hi0);
    const int n1 = __popcll(lo1) + __popcll(hi1);
    const int ntot = n0 + n1;
    unsigned long long below = (1ull << lane) - 1ull;
    int mypos = 0xFF;
    if (m0) mypos = (wr ? __popcll(lo0) : 0) + __popcll((wr ? hi0 : lo0) & below);
    else if (m1) mypos = n0 + (wr ? __popcll(lo1) : 0) + __popcll((wr ? hi1 : lo1) & below);
    __syncthreads();

    // --- phase 1: GEMM via global_load_lds 4-buffer pipeline ---
    const unsigned short* gAp = h16 + (size_t)blockIdx.x * T_ * D_ + (size_t)(tid >> 2) * D_ + (tid & 3) * 8;
    const unsigned short* gBp = dn16 + (size_t)(tid >> 2) * D_ + (tid & 3) * 8;

    int addrA[4], addrB[2];
#pragma unroll
    for (int m = 0; m < 4; ++m) {
        int row = 64 * wr + 16 * m + fr;
        addrA[m] = row * 32 + (kg ^ ((row >> 1) & 3)) * 8;
    }
#pragma unroll
    for (int n = 0; n < 2; ++n) {
        int row = 32 * wc + 16 * n + fr;
        addrB[n] = 4096 + row * 32 + (kg ^ ((row >> 1) & 3)) * 8;
    }

    f32x4 acc[4][2];
#pragma unroll
    for (int m = 0; m < 4; ++m)
#pragma unroll
        for (int n = 0; n < 2; ++n) acc[m][n] = (f32x4){0.f, 0.f, 0.f, 0.f};

    auto issue = [&](int it2) {
        const int bufo = (it2 & 3) * 8192;
        __builtin_amdgcn_global_load_lds((const void*)(gAp + it2 * 32),
                                         (void*)(&ldsbuf[bufo + w * 512]), 16, 0, 0);
        __builtin_amdgcn_global_load_lds((const void*)(gBp + it2 * 32),
                                         (void*)(&ldsbuf[bufo + 4096 + w * 512]), 16, 0, 0);
    };
    issue(0);
    issue(1);
    issue(2);

    for (int it = 0; it < NIT_; ++it) {
        if (it < NIT_ - 2)       asm volatile("s_waitcnt vmcnt(4)" ::: "memory");
        else if (it == NIT_ - 2) asm volatile("s_waitcnt vmcnt(2)" ::: "memory");
        else                     asm volatile("s_waitcnt vmcnt(0)" ::: "memory");
        __builtin_amdgcn_s_barrier();
        asm volatile("" ::: "memory");
        if (it + 3 < NIT_) issue(it + 3);
        const int bufo = (it & 3) * 8192;
        short8 af[4], bf_[2];
#pragma unroll
        for (int m = 0; m < 4; ++m)
            af[m] = *reinterpret_cast<const short8*>(&ldsbuf[bufo + addrA[m]]);
#pragma unroll
        for (int n = 0; n < 2; ++n)
            bf_[n] = *reinterpret_cast<const short8*>(&ldsbuf[bufo + addrB[n]]);
#pragma unroll
        for (int m = 0; m < 4; ++m)
#pragma unroll
            for (int n = 0; n < 2; ++n)
                acc[m][n] = __builtin_amdgcn_mfma_f32_16x16x32_bf16(af[m], bf_[n], acc[m][n], 0, 0, 0);
        asm volatile("" ::: "memory");
    }
    __syncthreads();   // all frag reads done; stage buffers now dead

    // epilogue: proj16 group-permuted (pos via shfl), sortable-u16
#pragma unroll
    for (int m = 0; m < 4; ++m) {
#pragma unroll
        for (int r = 0; r < 4; ++r) {
            int rowlane = 16 * m + kg * 4 + r;
            int pp = __shfl(mypos, rowlane);
            if (pp != 0xFF) {
#pragma unroll
                for (int n = 0; n < 2; ++n) {
                    int col = 32 * wc + 16 * n + fr;
                    unsigned bb = f2bf(acc[m][n][r]);
                    unsigned su = bb ^ ((bb >> 15) ? 0xFFFFu : 0x8000u);
                    proj16[pp * 128 + col] = (unsigned short)su;
                }
            }
        }
    }
    __syncthreads();

    // --- phase 2: ranking via sortable-u32 keys, single pass x 32 keys ---
    const int mmv = min(n0, n1);      // <= 64
    const int c = tid & 127;
    const int q = tid >> 7;           // 0..3
    const int pbase = q * 32;
    {
        unsigned kv[32];
        int cnt[32];
#pragma unroll
        for (int ii = 0; ii < 32; ++ii) {
            int p = pbase + ii;
            unsigned key = 0xFFFFFFFFu;
            if (p < ntot) {
                unsigned su = proj16[p * 128 + c];
                key = ((unsigned)(p >= n0) << 31) | (su << 8) | (unsigned)p;
            }
            kv[ii] = key;
            cnt[ii] = 0;
        }
        int lo, hi;
        if (pbase + 32 <= n0) { lo = 0;  hi = n0;   }
        else if (pbase >= n0) { lo = n0; hi = ntot; }
        else                  { lo = 0;  hi = ntot; }
        for (int j = lo; j < hi; ++j) {
            unsigned su = proj16[j * 128 + c];
            unsigned kw = ((unsigned)(j >= n0) << 31) | (su << 8) | (unsigned)j;
#pragma unroll
            for (int ii = 0; ii < 32; ++ii) cnt[ii] += (kw < kv[ii]) ? 1 : 0;
        }
#pragma unroll
        for (int ii = 0; ii < 32; ++ii) {
            int p = pbase + ii;
            if (p < ntot) {
                int rank = cnt[ii] - ((p >= n0 && lo == 0) ? n0 : 0);
                if (rank < mmv) {
                    unsigned char* buf = (p >= n0) ? yb : xb;
                    buf[rank * 128 + c] = (unsigned char)p;
                }
            }
        }
    }
    __syncthreads();

    // --- phase 3: paired diff per column, max over columns ---
    float part = 0.f;
    for (int r = q; r < mmv; r += 4) {
        unsigned sx = proj16[(int)xb[r * 128 + c] * 128 + c];
        unsigned sy = proj16[(int)yb[r * 128 + c] * 128 + c];
        unsigned bx = sx ^ ((sx >> 15) ? 0x8000u : 0xFFFFu);
        unsigned byv = sy ^ ((sy >> 15) ? 0x8000u : 0xFFFFu);
        part += fabsf(bf2f((unsigned short)bx) - bf2f((unsigned short)byv));
    }
    dred[tid] = part;
    __syncthreads();
    if (tid < 128) {
        float invm = 1.f / (float)max(mmv, 1);
        dred[tid] = (dred[tid] + dred[tid + 128] + dred[tid + 256] + dred[tid + 384]) * invm;
    }
    __syncthreads();
    if (tid < 64) {
        float m = fmaxf(dred[tid], dred[tid + 64]);
#pragma unroll
        for (int off = 32; off > 0; off >>= 1) m = fmaxf(m, __shfl_xor(m, off));
        if (tid == 0) d_ot[b] = m;
    }
}

// ---------------------------------------------------------------------------
// Kernel 4: head — C/S GEMV + gate + LayerNorm + logits.
// ---------------------------------------------------------------------------
__global__ __launch_bounds__(320) void k_head(const float* __restrict__ rep,
                                              const float* __restrict__ Wc,
                                              const float* __restrict__ bc,
                                              const float* __restrict__ Ws,
                                              const float* __restrict__ bs,
                                              const float* __restrict__ gate,
                                              const float* __restrict__ lng,
                                              const float* __restrict__ lnb,
                                              const float* __restrict__ Wcls,
                                              const float* __restrict__ bcls,
                                              const float* __restrict__ d_ot,
                                              float* __restrict__ out) {
    int b0 = blockIdx.x * 4;
    int tid = threadIdx.x;
    __shared__ __align__(16) float repS[4 * 1536];
    __shared__ float featS[4 * FEAT_];

    const float4* repg = reinterpret_cast<const float4*>(rep + (size_t)b0 * 1536);
    float4* repl = reinterpret_cast<float4*>(repS);
    for (int i = tid; i < 1536; i += 320) repl[i] = repg[i];
    __syncthreads();

    float g = 1.f / (1.f + expf(-gate[0]));

    {
        int o = tid;  // 0..319
        bool isC = o < CD_;
        const float* w = isC ? (Wc + (size_t)o * 1536) : (Ws + (size_t)(o - CD_) * 1536);
        float bias = isC ? bc[o] : bs[o - CD_];
        float scale = isC ? (1.f - g) : g;
        const float4* w4 = reinterpret_cast<const float4*>(w);
        float a0 = 0.f, a1 = 0.f, a2 = 0.f, a3 = 0.f;
        for (int k4 = 0; k4 < 384; ++k4) {
            float4 wv = w4[k4];
            float4 r0 = repl[k4];
            float4 r1 = repl[384 + k4];
            float4 r2 = repl[768 + k4];
            float4 r3 = repl[1152 + k4];
            a0 += fmaf(wv.x, r0.x, fmaf(wv.y, r0.y, fmaf(wv.z, r0.z, wv.w * r0.w)));
            a1 += fmaf(wv.x, r1.x, fmaf(wv.y, r1.y, fmaf(wv.z, r1.z, wv.w * r1.w)));
            a2 += fmaf(wv.x, r2.x, fmaf(wv.y, r2.y, fmaf(wv.z, r2.z, wv.w * r2.w)));
            a3 += fmaf(wv.x, r3.x, fmaf(wv.y, r3.y, fmaf(wv.z, r3.z, wv.w * r3.w)));
        }
        featS[0 * FEAT_ + o] = (a0 + bias) * scale;
        featS[1 * FEAT_ + o] = (a1 + bias) * scale;
        featS[2 * FEAT_ + o] = (a2 + bias) * scale;
        featS[3 * FEAT_ + o] = (a3 + bias) * scale;
    }
    if (tid < 4) featS[tid * FEAT_ + 320] = d_ot[b0 + tid];
    __syncthreads();

    int w = tid >> 6, lane = tid & 63;
    if (w < 4) {
        const float* f = featS + w * FEAT_;
        float s = 0.f, s2 = 0.f;
        for (int i = lane; i < FEAT_; i += 64) {
            float v = f[i];
            s += v;
            s2 = fmaf(v, v, s2);
        }
#pragma unroll
        for (int off = 32; off > 0; off >>= 1) {
            s += __shfl_xor(s, off);
            s2 += __shfl_xor(s2, off);
        }
        float mu = s * (1.f / (float)FEAT_);
        float var = fmaxf(s2 * (1.f / (float)FEAT_) - mu * mu, 0.f);
        float rstd = 1.0f / sqrtf(var + LN_EPS_);
        float l0 = 0.f, l1 = 0.f;
        for (int i = lane; i < FEAT_; i += 64) {
            float nv = (f[i] - mu) * rstd * lng[i] + lnb[i];
            l0 = fmaf(nv, Wcls[i], l0);
            l1 = fmaf(nv, Wcls[FEAT_ + i], l1);
        }
#pragma unroll
        for (int off = 32; off > 0; off >>= 1) {
            l0 += __shfl_xor(l0, off);
            l1 += __shfl_xor(l1, off);
        }
        if (lane == 0) {
            out[(size_t)(b0 + w) * 2 + 0] = l0 + bcls[0];
            out[(size_t)(b0 + w) * 2 + 1] = l1 + bcls[1];
        }
    }
}

// ---------------------------------------------------------------------------
// Kernel 5/6: ortho = mean((Wc @ Ws^T)^2)
// ---------------------------------------------------------------------------
__global__ __launch_bounds__(256) void k_ortho(const float* __restrict__ Wc,
                                               const float* __restrict__ Ws,
                                               float* __restrict__ part) {
    int i = blockIdx.x;
    int tid = threadIdx.x;
    __shared__ float wrow[1536];
    __shared__ float tmp[256];
    for (int k = tid; k < 1536; k += 256) wrow[k] = Wc[(size_t)i * 1536 + k];
    __syncthreads();
    int j = tid & 127, h = tid >> 7;
    const float* wsr = Ws + (size_t)j * 1536 + h * 768;
    const float* wr = wrow + h * 768;
    float s = 0.f;
    for (int k = 0; k < 768; ++k) s = fmaf(wr[k], wsr[k], s);
    tmp[tid] = s;
    __syncthreads();
    if (tid < 128) {
        float d = tmp[tid] + tmp[tid + 128];
        tmp[tid] = d * d;
    }
    __syncthreads();
    for (int off = 64; off > 0; off >>= 1) {
        if (tid < off) tmp[tid] += tmp[tid + off];
        __syncthreads();
    }
    if (tid == 0) part[i] = tmp[0];
}

__global__ __launch_bounds__(256) void k_ortho2(const float* __restrict__ part,
                                                float* __restrict__ out) {
    int tid = threadIdx.x;
    __shared__ float red[256];
    red[tid] = (tid < CD_) ? part[tid] : 0.f;
    __syncthreads();
    for (int off = 128; off > 0; off >>= 1) {
        if (tid < off) red[tid] += red[tid + off];
        __syncthreads();
    }
    if (tid == 0) out[(size_t)B_ * 2] = red[0] / (float)(CD_ * SD_);
}

// ---------------------------------------------------------------------------
extern "C" void kernel_launch(void* const* d_in, const int* in_sizes, int n_in,
                              void* d_out, int out_size, void* d_ws, size_t ws_size,
                              hipStream_t stream) {
    const float* H    = (const float*)d_in[0];
    const int*   tt   = (const int*)d_in[1];
    const int*   attn = (const int*)d_in[2];
    const float* Wc   = (const float*)d_in[3];
    const float* bc   = (const float*)d_in[4];
    const float* Ws   = (const float*)d_in[5];
    const float* bs   = (const float*)d_in[6];
    const float* gate = (const float*)d_in[7];
    const float* lng  = (const float*)d_in[8];
    const float* lnb  = (const float*)d_in[9];
    const float* Wcls = (const float*)d_in[10];
    const float* bcls = (const float*)d_in[11];
    const float* dirs = (const float*)d_in[12];

    float* ws    = (float*)d_ws;
    float* rep   = ws;                                      // [B][1536] fp32
    unsigned short* dn16 = (unsigned short*)(ws + REP_SZ);  // [P][D] bf16 (swizzled)
    float* dot   = ws + REP_SZ + DN16_FLT;                  // [B]
    float* part  = dot + B_;                                // [CD]
    unsigned short* h16 = (unsigned short*)(ws + FIXED_FLT);// [chunk][T][D] bf16 (swizzled)
    float* out   = (float*)d_out;

    // batch chunk size limited by workspace
    size_t availB = (ws_size > FIXED_FLT * 4) ? (ws_size - FIXED_FLT * 4) : 0;
    int maxB = (int)(availB / H16_PER_B);
    int chunk = B_;
    while (chunk > maxB && chunk > 1) chunk >>= 1;
    if (chunk > maxB) chunk = 1;

    k_dirs<<<P_, 256, 0, stream>>>(dirs, dn16);
    for (int c = 0; c < B_; c += chunk) {
        int nb = min(chunk, B_ - c);
        k_prep<<<nb, 768, 0, stream>>>(H, tt, attn, rep, h16, c);
        k_projsort<<<nb, 512, 0, stream>>>(tt, attn, h16, dn16, dot, c);
    }
    k_head<<<B_ / 4, 320, 0, stream>>>(rep, Wc, bc, Ws, bs, gate, lng, lnb, Wcls, bcls, dot, out);
    k_ortho<<<CD_, 256, 0, stream>>>(Wc, Ws, part);
    k_ortho2<<<1, 256, 0, stream>>>(part, out);
}